// Round 7
// baseline (528.115 us; speedup 1.0000x reference)
//
#include <hip/hip_runtime.h>
#include <hip/hip_bf16.h>
#include <stdint.h>

typedef __attribute__((ext_vector_type(8))) short short8;
typedef __attribute__((ext_vector_type(4))) short bf16x4;
typedef __attribute__((ext_vector_type(4))) float f32x4;

#define S_LEN   4096
#define HID_DIM 2048
#define NHEAD   16
#define NKV     4
#define DHEAD   128
#define QPG     4
#define GROUP   768   // (QPG+2)*DHEAD
#define TOTAL   3072  // NKV*GROUP

#define NSLOT   336   // 256 heavy + 80 light (pairs 11..15)

__device__ __forceinline__ ushort f2bf(float f) {
    union { float f; uint32_t u; } c; c.f = f;
    uint32_t u = c.u;
    u += 0x7fff + ((u >> 16) & 1);   // RNE
    return (ushort)(u >> 16);
}

__device__ __forceinline__ uint32_t cvt_pk_bf16(float lo, float hi) {
    uint32_t r;
    asm("v_cvt_pk_bf16_f32 %0, %1, %2" : "=v"(r) : "v"(lo), "v"(hi));
    return r;
}

__device__ __forceinline__ void gld_lds16(const void* g, void* l) {
    __builtin_amdgcn_global_load_lds(
        (const __attribute__((address_space(1))) void*)g,
        (__attribute__((address_space(3))) void*)l, 16, 0, 0);
}

// LDS-only barrier: staged K/V visibility via lgkmcnt(0); register-destined
// global prefetch loads may stay in flight (R6: neutral, kept as correct-min).
__device__ __forceinline__ void lds_barrier() {
    asm volatile("s_waitcnt lgkmcnt(0)\n\ts_barrier" ::: "memory");
}

// ---------------------------------------------------------------------------
// fp32 -> bf16 convert. mode 1: scale q-head rows of wqkv by 1/sqrt(D)
// ---------------------------------------------------------------------------
__global__ __launch_bounds__(256)
void cvt_f32_bf16(const float* __restrict__ src, ushort* __restrict__ dst,
                  int n4, int mode)
{
    int i = blockIdx.x * blockDim.x + threadIdx.x;
    int stride = gridDim.x * blockDim.x;
    for (; i < n4; i += stride) {
        float sc = 1.0f;
        if (mode == 1) {
            int row = i >> 9;                      // (i*4)/2048
            sc = ((row % GROUP) < QPG * DHEAD) ? 0.088388347648318447f : 1.0f;
        }
        float4 v = ((const float4*)src)[i];
        ushort4 o;
        o.x = f2bf(v.x * sc); o.y = f2bf(v.y * sc);
        o.z = f2bf(v.z * sc); o.w = f2bf(v.w * sc);
        ((ushort4*)dst)[i] = o;
    }
}

__global__ __launch_bounds__(256)
void zero_f4(float4* __restrict__ p, int n4)
{
    int i = blockIdx.x * blockDim.x + threadIdx.x;
    int stride = gridDim.x * blockDim.x;
    float4 z = {0.f, 0.f, 0.f, 0.f};
    for (; i < n4; i += stride) p[i] = z;
}

// ---------------------------------------------------------------------------
// C[M,N] = A[M,K] * B[N,K]^T (bf16 in, fp32 accum). m97-style staging.
// ---------------------------------------------------------------------------
__device__ __forceinline__ void store_c(ushort* C, size_t idx, float v) { C[idx] = f2bf(v); }
__device__ __forceinline__ void store_c(float*  C, size_t idx, float v) { C[idx] = v; }

template <typename OutT, bool WRITE_VT>
__global__ __launch_bounds__(256, 2)
void gemm_bt(const ushort* __restrict__ A, const ushort* __restrict__ B,
             OutT* __restrict__ C, ushort* __restrict__ VT,
             int M, int N, int K)
{
    __shared__ alignas(16) ushort Asl[128 * 32];
    __shared__ alignas(16) ushort Bsl[128 * 32];

    const int tid  = threadIdx.x;
    const int wave = tid >> 6;
    const int lane = tid & 63;
    const int quad = lane >> 4;
    const int l15  = lane & 15;
    const int wr   = wave >> 1;
    const int wc   = wave & 1;
    const int m0   = blockIdx.y * 128;
    const int n0   = blockIdx.x * 128;

    f32x4 acc[4][4];
#pragma unroll
    for (int i = 0; i < 4; i++)
#pragma unroll
        for (int j = 0; j < 4; j++) acc[i][j] = (f32x4)0.0f;

    for (int kb = 0; kb < K; kb += 32) {
        __syncthreads();
#pragma unroll
        for (int r = 0; r < 2; r++) {
            int idx = tid + r * 256;
            int row = idx >> 2, c8 = idx & 3;
            char* la = (char*)Asl + (size_t)(wave * 64 + r * 256) * 16;
            char* lb = (char*)Bsl + (size_t)(wave * 64 + r * 256) * 16;
            gld_lds16(A + (size_t)(m0 + row) * K + kb + c8 * 8, la);
            gld_lds16(B + (size_t)(n0 + row) * K + kb + c8 * 8, lb);
        }
        __syncthreads();

        short8 af[4], bf[4];
#pragma unroll
        for (int i = 0; i < 4; i++)
            af[i] = *(const short8*)(&Asl[(wr * 64 + i * 16 + l15) * 32 + quad * 8]);
#pragma unroll
        for (int j = 0; j < 4; j++)
            bf[j] = *(const short8*)(&Bsl[(wc * 64 + j * 16 + l15) * 32 + quad * 8]);
#pragma unroll
        for (int i = 0; i < 4; i++)
#pragma unroll
            for (int j = 0; j < 4; j++)
                acc[i][j] = __builtin_amdgcn_mfma_f32_16x16x32_bf16(
                    af[i], bf[j], acc[i][j], 0, 0, 0);
    }

#pragma unroll
    for (int i = 0; i < 4; i++)
#pragma unroll
        for (int j = 0; j < 4; j++)
#pragma unroll
            for (int r = 0; r < 4; r++) {
                int row = m0 + wr * 64 + i * 16 + quad * 4 + r;
                int col = n0 + wc * 64 + j * 16 + l15;
                store_c(C, (size_t)row * N + col, acc[i][j][r]);
            }

    if (WRITE_VT) {
        int cb = n0 >> 7;
        if (cb % 6 == 5) {          // V-region column block
            int g = cb / 6;
#pragma unroll
            for (int i = 0; i < 4; i++)
#pragma unroll
                for (int j = 0; j < 4; j++) {
                    int d    = wc * 64 + j * 16 + l15;
                    int row0 = m0 + wr * 64 + i * 16 + quad * 4;
                    ushort4 pk;
                    pk.x = f2bf(acc[i][j][0]); pk.y = f2bf(acc[i][j][1]);
                    pk.z = f2bf(acc[i][j][2]); pk.w = f2bf(acc[i][j][3]);
                    *(ushort4*)(VT + (size_t)(g * 128 + d) * S_LEN + row0) = pk;
                }
        }
    }
}

// ---------------------------------------------------------------------------
// Causal GQA flash attention. SWAPPED-QK^T version of the R4 dbuf pipeline:
//   S^T = mfma_16x16x32(K, Q)  -> lane holds S^T[kv=quad*4+r+16ki][q=l15+16qi]
//   softmax + cvt_pk in-lane   -> P^T packed bf16, NO LDS round-trip
//   O^T += mfma_16x16x16(V^T, P) -- the 16x16x16 B-frag wants k=quad*4..+3,
//   exactly the swapped S^T register layout, so P never leaves the lane.
// Pl LDS deleted (-9.2 KB -> 37,888 B total) -> 3 blocks/CU fit; grid
// regridded to 768 co-terminating blocks = 3x256 exactly (R5's verified
// thirds-of-44 segmentation over heavy(128-4p)++light(4p+4) = 132 units,
// head-major decode head=b/48 for KV locality, NSLOT=336).
// Epilogue: O^T layout makes d contiguous in r -> packed ushort4 stores.
// launch_bounds stays (256,2): min-waves 3/4 spilled (R1/R2).
// ---------------------------------------------------------------------------
__global__ __launch_bounds__(256, 2)
void flash_attn(const ushort* __restrict__ qkv, const ushort* __restrict__ VT,
                ushort* __restrict__ out, float* __restrict__ o_slot,
                float* __restrict__ l_slot)
{
    const int b     = blockIdx.x;
    const int head  = b / 48;                 // head-major
    const int r48   = b - head * 48;
    const int pair  = r48 / 3;                // 0..15
    const int third = r48 - pair * 3;         // 0..2

    const int g    = head >> 2;
    const int qh   = head & 3;
    const int H    = 128 - 4 * pair;          // heavy strip tiles (68..128)
    const int L    = 4 * pair + 4;            // light strip tiles (4..64)
    const int c0   = third * 44;
    const int c1   = c0 + 44;

    const int tid  = threadIdx.x;
    const int wave = tid >> 6;
    const int lane = tid & 63;
    const int quad = lane >> 4;
    const int l15  = lane & 15;

    __shared__ alignas(16) ushort Kl[2][32][136];   // [buf][j][d]   17,408 B
    __shared__ alignas(16) ushort Vt[2][128][40];   // [buf][d][j]   20,480 B

    int seg_p[2], seg_t0[2], seg_t1[2], seg_slot[2];
    int nseg = 0;
    {
        int h1 = (c1 < H) ? c1 : H;           // heavy piece [c0, h1)
        if (c0 < h1) {
            seg_p[nseg] = 31 - pair; seg_t0[nseg] = c0; seg_t1[nseg] = h1;
            seg_slot[nseg] = head * 16 + pair;          // heavy slot 0..255
            nseg++;
        }
        int l0 = (c0 > H) ? c0 : H;           // light piece [l0, c1) global units
        if (l0 < c1) {
            int lt0 = l0 - H, lt1 = c1 - H;
            int whole = (lt0 == 0) & (lt1 == L);        // pairs <= 10
            seg_p[nseg] = pair; seg_t0[nseg] = lt0; seg_t1[nseg] = lt1;
            seg_slot[nseg] = whole ? -1 : (256 + head * 5 + (pair - 11));
            nseg++;
        }
    }

    const int koff = g * GROUP + QPG * DHEAD;

    for (int s = 0; s < nseg; s++) {
        const int t0 = seg_t0[s];
        const int t1 = seg_t1[s];
        const int q0 = seg_p[s] * 128;

        // Q fragments (B-operand: lane q-row = l15, k-chunk = quad*8)
        short8 qf[2][4];
#pragma unroll
        for (int qi = 0; qi < 2; qi++) {
            int row = q0 + wave * 32 + qi * 16 + l15;
            const ushort* qp = qkv + (size_t)row * TOTAL + g * GROUP + qh * DHEAD + quad * 8;
#pragma unroll
            for (int ks = 0; ks < 4; ks++)
                qf[qi][ks] = *(const short8*)(qp + ks * 32);
        }

        f32x4 o[2][8];                        // O^T acc: [qi][df]
#pragma unroll
        for (int qi = 0; qi < 2; qi++)
#pragma unroll
            for (int df = 0; df < 8; df++) o[qi][df] = (f32x4)0.0f;
        float l_vec[2] = {0.0f, 0.0f};

        // per-thread staging slots (32-row tile: 512 f4 K + 512 f4 V)
        const int kr = tid >> 4, kc = tid & 15;       // K rows 0..15 (+16 on r=1)
        const int vd = tid >> 2, vc = tid & 3;        // V rows 0..63 (+64 on r=1)

        float4 kpre[2], vpre[2];
        // prologue: load tile t0, write buf 0, prefetch t0+1
#pragma unroll
        for (int r = 0; r < 2; r++) {
            kpre[r] = *(const float4*)(qkv + (size_t)(t0 * 32 + kr + r * 16) * TOTAL + koff + kc * 8);
            vpre[r] = *(const float4*)(VT + (size_t)(g * 128 + vd + r * 64) * S_LEN + t0 * 32 + vc * 8);
        }
#pragma unroll
        for (int r = 0; r < 2; r++) {
            *(float4*)(&Kl[0][kr + r * 16][kc * 8]) = kpre[r];
            *(float4*)(&Vt[0][vd + r * 64][vc * 8]) = vpre[r];
        }
        if (t0 + 1 < t1) {
            const int j1 = (t0 + 1) * 32;
#pragma unroll
            for (int r = 0; r < 2; r++) {
                kpre[r] = *(const float4*)(qkv + (size_t)(j1 + kr + r * 16) * TOTAL + koff + kc * 8);
                vpre[r] = *(const float4*)(VT + (size_t)(g * 128 + vd + r * 64) * S_LEN + j1 + vc * 8);
            }
        }
        __syncthreads();

        for (int t = t0; t < t1; t++) {
            const int cur = (t - t0) & 1;

            // stage tile t+1 into the other buffer (overlaps this compute)
            if (t + 1 < t1) {
#pragma unroll
                for (int r = 0; r < 2; r++) {
                    *(float4*)(&Kl[cur ^ 1][kr + r * 16][kc * 8]) = kpre[r];
                    *(float4*)(&Vt[cur ^ 1][vd + r * 64][vc * 8]) = vpre[r];
                }
                if (t + 2 < t1) {
                    const int j2 = (t + 2) * 32;
#pragma unroll
                    for (int r = 0; r < 2; r++) {
                        kpre[r] = *(const float4*)(qkv + (size_t)(j2 + kr + r * 16) * TOTAL + koff + kc * 8);
                        vpre[r] = *(const float4*)(VT + (size_t)(g * 128 + vd + r * 64) * S_LEN + j2 + vc * 8);
                    }
                }
            }

            const int j0 = t * 32;
            // S^T = K Q^T : sacc[ki][qi], lane: kv = quad*4+r (+16ki), q = l15 (+16qi)
            f32x4 sacc[2][2];
#pragma unroll
            for (int ki = 0; ki < 2; ki++)
#pragma unroll
                for (int qi = 0; qi < 2; qi++) sacc[ki][qi] = (f32x4)0.0f;
            __builtin_amdgcn_s_setprio(1);
#pragma unroll
            for (int ki = 0; ki < 2; ki++)
#pragma unroll
                for (int ks = 0; ks < 4; ks++) {
                    short8 kf = *(const short8*)(&Kl[cur][ki * 16 + l15][ks * 32 + quad * 8]);
#pragma unroll
                    for (int qi = 0; qi < 2; qi++)
                        sacc[ki][qi] = __builtin_amdgcn_mfma_f32_16x16x32_bf16(
                            kf, qf[qi][ks], sacc[ki][qi], 0, 0, 0);
                }
            __builtin_amdgcn_s_setprio(0);

            // exp (no max) + causal mask + l accumulation + in-lane bf16 pack
            bf16x4 pb[2][2];                  // [qi][ki] packed P^T
#pragma unroll
            for (int qi = 0; qi < 2; qi++) {
                const int qmin = q0 + wave * 32 + qi * 16;   // wave-uniform
                float rs = 0.0f;
                if (j0 + 31 > qmin) {
                    const int q_g = qmin + l15;
#pragma unroll
                    for (int ki = 0; ki < 2; ki++)
#pragma unroll
                        for (int r = 0; r < 4; r++) {
                            float e = __expf(sacc[ki][qi][r]);
                            int kv_g = j0 + ki * 16 + quad * 4 + r;
                            e = (kv_g > q_g) ? 0.0f : e;
                            sacc[ki][qi][r] = e;
                            rs += e;
                        }
                } else {
#pragma unroll
                    for (int ki = 0; ki < 2; ki++)
#pragma unroll
                        for (int r = 0; r < 4; r++) {
                            float e = __expf(sacc[ki][qi][r]);
                            sacc[ki][qi][r] = e;
                            rs += e;
                        }
                }
                l_vec[qi] += rs;
#pragma unroll
                for (int ki = 0; ki < 2; ki++) {
                    union { uint32_t u[2]; bf16x4 v; } pw;
                    pw.u[0] = cvt_pk_bf16(sacc[ki][qi][0], sacc[ki][qi][1]);
                    pw.u[1] = cvt_pk_bf16(sacc[ki][qi][2], sacc[ki][qi][3]);
                    pb[qi][ki] = pw.v;
                }
            }

            // O^T += V^T P : A = V^T (lane: d=l15, kv=quad*4..+3 per ki),
            //                B = P   (lane: q=l15, kv=quad*4..+3) -- in regs!
            __builtin_amdgcn_s_setprio(1);
#pragma unroll
            for (int df = 0; df < 8; df++) {
#pragma unroll
                for (int ki = 0; ki < 2; ki++) {
                    bf16x4 vf = *(const bf16x4*)(&Vt[cur][df * 16 + l15][ki * 16 + quad * 4]);
#pragma unroll
                    for (int qi = 0; qi < 2; qi++)
                        asm("v_mfma_f32_16x16x16_bf16 %0, %1, %2, %0"
                            : "+v"(o[qi][df]) : "v"(vf), "v"(pb[qi][ki]));
                }
            }
            __builtin_amdgcn_s_setprio(0);

            lds_barrier();   // buf^1 staged; prefetch stays in flight
        }

        // epilogue. O^T lane layout: d = df*16 + quad*4 + r, q = l15 + 16qi.
        if (seg_slot[s] >= 0) {
            const int sslot = seg_slot[s];
#pragma unroll
            for (int qi = 0; qi < 2; qi++) {
                float l = l_vec[qi];
                l += __shfl_xor(l, 16);
                l += __shfl_xor(l, 32);
                int row_l = wave * 32 + qi * 16 + l15;    // 0..127
                if (lane < 16)
                    atomicAdd(&l_slot[sslot * 128 + row_l], l);
#pragma unroll
                for (int df = 0; df < 8; df++)
#pragma unroll
                    for (int r = 0; r < 4; r++)
                        atomicAdd(&o_slot[((size_t)sslot * 128 + row_l) * 128
                                          + df * 16 + quad * 4 + r], o[qi][df][r]);
            }
        } else {
#pragma unroll
            for (int qi = 0; qi < 2; qi++) {
                float l = l_vec[qi];
                l += __shfl_xor(l, 16);
                l += __shfl_xor(l, 32);
                float inv = 1.0f / l;
                int row = q0 + wave * 32 + qi * 16 + l15;
#pragma unroll
                for (int df = 0; df < 8; df++) {
                    ushort4 pk4;
                    pk4.x = f2bf(o[qi][df][0] * inv);
                    pk4.y = f2bf(o[qi][df][1] * inv);
                    pk4.z = f2bf(o[qi][df][2] * inv);
                    pk4.w = f2bf(o[qi][df][3] * inv);
                    *(ushort4*)(out + (size_t)row * (NHEAD * DHEAD) + head * DHEAD
                                + df * 16 + quad * 4) = pk4;
                }
            }
        }
    }
}

// ---------------------------------------------------------------------------
// Normalize split-strip slots -> attn (bf16)
// slots 0..255: heavy strip of (head, pair) -> q0 = (31-pair)*128
// slots 256..335: light strips of pairs 11..15 -> q0 = pair*128
// ---------------------------------------------------------------------------
__global__ __launch_bounds__(256)
void fixup_norm(const float* __restrict__ o_slot, const float* __restrict__ l_slot,
                ushort* __restrict__ attn)
{
    const int slot = blockIdx.x;          // 0..335
    int head, q0;
    if (slot < 256) {
        head = slot >> 4;
        q0   = (31 - (slot & 15)) * 128;
    } else {
        int s = slot - 256;
        head = s / 5;
        q0   = (11 + (s - head * 5)) * 128;
    }
    const int t = threadIdx.x;
#pragma unroll 4
    for (int i = 0; i < 64; i++) {
        int idx = i * 256 + t;            // 0..16383
        int row = idx >> 7, d = idx & 127;
        float l = l_slot[slot * 128 + row];
        float v = o_slot[(size_t)slot * 16384 + idx] / l;
        attn[(size_t)(q0 + row) * HID_DIM + head * DHEAD + d] = f2bf(v);
    }
}

// ---------------------------------------------------------------------------
extern "C" void kernel_launch(void* const* d_in, const int* in_sizes, int n_in,
                              void* d_out, int out_size, void* d_ws, size_t ws_size,
                              hipStream_t stream)
{
    const float* x     = (const float*)d_in[0];
    const float* wqkv  = (const float*)d_in[1];
    const float* wproj = (const float*)d_in[2];
    float* outp = (float*)d_out;

    const size_t n_x     = (size_t)S_LEN * HID_DIM;     // 8,388,608
    const size_t n_wqkv  = (size_t)TOTAL * HID_DIM;     // 6,291,456
    const size_t n_wproj = (size_t)HID_DIM * HID_DIM;   // 4,194,304
    const size_t n_qkv   = (size_t)S_LEN * TOTAL;
    const size_t n_attn  = (size_t)S_LEN * HID_DIM;

    ushort* xb     = (ushort*)d_ws;                     // dead after GEMM1
    ushort* wqkvb  = xb + n_x;                          // dead after GEMM1
    ushort* qkv    = wqkvb + n_wqkv;
    ushort* attn   = qkv + n_qkv;
    ushort* vt     = attn + n_attn;                     // [4][128][4096]
    // reuse dead regions during/after flash:
    // o_slot+l_slot = 336*16384*4 + 336*128*4 = 22.19 MB <= xb+wqkvb (29.36 MB)
    float* o_slot  = (float*)d_ws;
    float* l_slot  = o_slot + (size_t)NSLOT * 16384;
    ushort* wprojb = wqkvb;                             // converted after fixup

    cvt_f32_bf16<<<2048, 256, 0, stream>>>(x, xb, (int)(n_x / 4), 0);
    cvt_f32_bf16<<<2048, 256, 0, stream>>>(wqkv, wqkvb, (int)(n_wqkv / 4), 1);

    // 1) qkv = x @ wqkv^T (+ V^T side-write)
    gemm_bt<ushort, true><<<dim3(TOTAL / 128, S_LEN / 128), 256, 0, stream>>>(
        xb, wqkvb, qkv, vt, S_LEN, TOTAL, HID_DIM);

    // zero the partial-accumulation slots (xb/wqkvb now dead); o+l contiguous
    zero_f4<<<2048, 256, 0, stream>>>((float4*)o_slot,
                                      (int)(((size_t)NSLOT * 16384 + NSLOT * 128) / 4));

    // 2) attention (768 co-terminating blocks = 3/CU, swapped-QK^T pipeline)
    flash_attn<<<768, 256, 0, stream>>>(qkv, vt, attn, o_slot, l_slot);
    fixup_norm<<<NSLOT, 256, 0, stream>>>(o_slot, l_slot, attn);

    // 3) convert wproj (into dead wqkvb region), then out = attn @ wproj^T
    cvt_f32_bf16<<<2048, 256, 0, stream>>>(wproj, wprojb, (int)(n_wproj / 4), 0);
    gemm_bt<float, false><<<dim3(HID_DIM / 128, S_LEN / 128), 256, 0, stream>>>(
        attn, wprojb, outp, nullptr, S_LEN, HID_DIM, HID_DIM);
}

// Round 8
// 382.036 us; speedup vs baseline: 1.3824x; 1.3824x over previous
//
#include <hip/hip_runtime.h>
#include <hip/hip_bf16.h>
#include <stdint.h>

typedef __attribute__((ext_vector_type(8))) short short8;
typedef __attribute__((ext_vector_type(4))) float f32x4;

#define S_LEN   4096
#define HID_DIM 2048
#define NHEAD   16
#define NKV     4
#define DHEAD   128
#define QPG     4
#define GROUP   768   // (QPG+2)*DHEAD
#define TOTAL   3072  // NKV*GROUP

#define NSLOT   192   // 128 heavy + 64 light (pairs 4..7), 256-row slots

__device__ __forceinline__ ushort f2bf(float f) {
    union { float f; uint32_t u; } c; c.f = f;
    uint32_t u = c.u;
    u += 0x7fff + ((u >> 16) & 1);   // RNE
    return (ushort)(u >> 16);
}

__device__ __forceinline__ void gld_lds16(const void* g, void* l) {
    __builtin_amdgcn_global_load_lds(
        (const __attribute__((address_space(1))) void*)g,
        (__attribute__((address_space(3))) void*)l, 16, 0, 0);
}

// LDS-only barrier: staged K/V visibility via lgkmcnt(0); register-destined
// global prefetch loads may stay in flight (R6: neutral vs full drain).
__device__ __forceinline__ void lds_barrier() {
    asm volatile("s_waitcnt lgkmcnt(0)\n\ts_barrier" ::: "memory");
}

// ---------------------------------------------------------------------------
// fp32 -> bf16 convert. mode 1: scale q-head rows of wqkv by 1/sqrt(D)
// ---------------------------------------------------------------------------
__global__ __launch_bounds__(256)
void cvt_f32_bf16(const float* __restrict__ src, ushort* __restrict__ dst,
                  int n4, int mode)
{
    int i = blockIdx.x * blockDim.x + threadIdx.x;
    int stride = gridDim.x * blockDim.x;
    for (; i < n4; i += stride) {
        float sc = 1.0f;
        if (mode == 1) {
            int row = i >> 9;                      // (i*4)/2048
            sc = ((row % GROUP) < QPG * DHEAD) ? 0.088388347648318447f : 1.0f;
        }
        float4 v = ((const float4*)src)[i];
        ushort4 o;
        o.x = f2bf(v.x * sc); o.y = f2bf(v.y * sc);
        o.z = f2bf(v.z * sc); o.w = f2bf(v.w * sc);
        ((ushort4*)dst)[i] = o;
    }
}

__global__ __launch_bounds__(256)
void zero_f4(float4* __restrict__ p, int n4)
{
    int i = blockIdx.x * blockDim.x + threadIdx.x;
    int stride = gridDim.x * blockDim.x;
    float4 z = {0.f, 0.f, 0.f, 0.f};
    for (; i < n4; i += stride) p[i] = z;
}

// ---------------------------------------------------------------------------
// C[M,N] = A[M,K] * B[N,K]^T (bf16 in, fp32 accum). m97-style staging.
// ---------------------------------------------------------------------------
__device__ __forceinline__ void store_c(ushort* C, size_t idx, float v) { C[idx] = f2bf(v); }
__device__ __forceinline__ void store_c(float*  C, size_t idx, float v) { C[idx] = v; }

template <typename OutT, bool WRITE_VT>
__global__ __launch_bounds__(256, 2)
void gemm_bt(const ushort* __restrict__ A, const ushort* __restrict__ B,
             OutT* __restrict__ C, ushort* __restrict__ VT,
             int M, int N, int K)
{
    __shared__ alignas(16) ushort Asl[128 * 32];
    __shared__ alignas(16) ushort Bsl[128 * 32];

    const int tid  = threadIdx.x;
    const int wave = tid >> 6;
    const int lane = tid & 63;
    const int quad = lane >> 4;
    const int l15  = lane & 15;
    const int wr   = wave >> 1;
    const int wc   = wave & 1;
    const int m0   = blockIdx.y * 128;
    const int n0   = blockIdx.x * 128;

    f32x4 acc[4][4];
#pragma unroll
    for (int i = 0; i < 4; i++)
#pragma unroll
        for (int j = 0; j < 4; j++) acc[i][j] = (f32x4)0.0f;

    for (int kb = 0; kb < K; kb += 32) {
        __syncthreads();
#pragma unroll
        for (int r = 0; r < 2; r++) {
            int idx = tid + r * 256;
            int row = idx >> 2, c8 = idx & 3;
            char* la = (char*)Asl + (size_t)(wave * 64 + r * 256) * 16;
            char* lb = (char*)Bsl + (size_t)(wave * 64 + r * 256) * 16;
            gld_lds16(A + (size_t)(m0 + row) * K + kb + c8 * 8, la);
            gld_lds16(B + (size_t)(n0 + row) * K + kb + c8 * 8, lb);
        }
        __syncthreads();

        short8 af[4], bf[4];
#pragma unroll
        for (int i = 0; i < 4; i++)
            af[i] = *(const short8*)(&Asl[(wr * 64 + i * 16 + l15) * 32 + quad * 8]);
#pragma unroll
        for (int j = 0; j < 4; j++)
            bf[j] = *(const short8*)(&Bsl[(wc * 64 + j * 16 + l15) * 32 + quad * 8]);
#pragma unroll
        for (int i = 0; i < 4; i++)
#pragma unroll
            for (int j = 0; j < 4; j++)
                acc[i][j] = __builtin_amdgcn_mfma_f32_16x16x32_bf16(
                    af[i], bf[j], acc[i][j], 0, 0, 0);
    }

#pragma unroll
    for (int i = 0; i < 4; i++)
#pragma unroll
        for (int j = 0; j < 4; j++)
#pragma unroll
            for (int r = 0; r < 4; r++) {
                int row = m0 + wr * 64 + i * 16 + quad * 4 + r;
                int col = n0 + wc * 64 + j * 16 + l15;
                store_c(C, (size_t)row * N + col, acc[i][j][r]);
            }

    if (WRITE_VT) {
        int cb = n0 >> 7;
        if (cb % 6 == 5) {          // V-region column block
            int g = cb / 6;
#pragma unroll
            for (int i = 0; i < 4; i++)
#pragma unroll
                for (int j = 0; j < 4; j++) {
                    int d    = wc * 64 + j * 16 + l15;
                    int row0 = m0 + wr * 64 + i * 16 + quad * 4;
                    ushort4 pk;
                    pk.x = f2bf(acc[i][j][0]); pk.y = f2bf(acc[i][j][1]);
                    pk.z = f2bf(acc[i][j][2]); pk.w = f2bf(acc[i][j][3]);
                    *(ushort4*)(VT + (size_t)(g * 128 + d) * S_LEN + row0) = pk;
                }
        }
    }
}

// ---------------------------------------------------------------------------
// Causal GQA flash attention. R4/R6's proven dbuf pipeline body (32-row KV
// tiles, 1 lgkm-barrier/tile, stage t+1 overlaps compute t, setprio, Pl
// per-wave LDS P) widened to 8-WAVE BLOCKS (512 thr, 256-row Q strips):
// each staged KV tile now feeds 2x the q-rows, and 2 blocks/CU co-resident
// give 16 waves/CU (4/SIMD) -- double R4's latency hiding. R2 proved this
// geometry's correctness; its failure was the (512,4) VGPR-64 cap, so
// launch_bounds is (512,2) (cap 256: cannot crush; body compiles ~100).
// Strips of 256 rows need 8s+8 32-row tiles. Pair p: heavy 15-p
// (H = 128-8p) ++ light p (L = 8p+8), H+L = 136 = 4*34. Block
// (head, pair, quarter) covers units [34q, 34q+34), head-major decode.
// Light whole for p<=3 (inline normalize); split lights (p 4..7) ->
// 64 extra atomic slots; NSLOT = 192, 256-row slots.
// LDS 56,320 B -> 2 blocks/CU even at 8 KB alloc granularity.
// ---------------------------------------------------------------------------
__global__ __launch_bounds__(512, 2)
void flash_attn(const ushort* __restrict__ qkv, const ushort* __restrict__ VT,
                ushort* __restrict__ out, float* __restrict__ o_slot,
                float* __restrict__ l_slot)
{
    const int b    = blockIdx.x;
    const int head = b >> 5;                  // head-major
    const int pair = (b >> 2) & 7;            // 0..7
    const int quar = b & 3;                   // 0..3

    const int g    = head >> 2;
    const int qh   = head & 3;
    const int H    = 128 - 8 * pair;          // heavy strip tiles (72..128)
    const int L    = 8 * pair + 8;            // light strip tiles (8..64)
    const int c0   = quar * 34;
    const int c1   = c0 + 34;

    const int tid  = threadIdx.x;
    const int wave = tid >> 6;                // 0..7
    const int lane = tid & 63;
    const int quad = lane >> 4;
    const int l15  = lane & 15;

    __shared__ alignas(16) ushort Kl[2][32][136];   // [buf][j][d]   17,408 B
    __shared__ alignas(16) ushort Vt[2][128][40];   // [buf][d][j]   20,480 B
    __shared__ alignas(16) ushort Pl[8][32][36];    // per-wave P    18,432 B

    int seg_s[2], seg_t0[2], seg_t1[2], seg_slot[2];
    int nseg = 0;
    {
        int h1 = (c1 < H) ? c1 : H;           // heavy piece [c0, h1)
        if (c0 < h1) {
            seg_s[nseg] = 15 - pair; seg_t0[nseg] = c0; seg_t1[nseg] = h1;
            seg_slot[nseg] = head * 8 + pair;           // heavy slot 0..127
            nseg++;
        }
        int l0 = (c0 > H) ? c0 : H;           // light piece [l0, c1) global units
        if (l0 < c1) {
            int lt0 = l0 - H, lt1 = c1 - H;
            int whole = (lt0 == 0) & (lt1 == L);        // pairs 0..3
            seg_s[nseg] = pair; seg_t0[nseg] = lt0; seg_t1[nseg] = lt1;
            seg_slot[nseg] = whole ? -1 : (128 + head * 4 + (pair - 4));
            nseg++;
        }
    }

    const int koff = g * GROUP + QPG * DHEAD;

    for (int s = 0; s < nseg; s++) {
        const int t0 = seg_t0[s];
        const int t1 = seg_t1[s];
        const int q0 = seg_s[s] * 256;

        // Q fragments: 32 rows/wave (8 waves = 256-row strip), 2 frags, D=128
        short8 qf[2][4];
#pragma unroll
        for (int mi = 0; mi < 2; mi++) {
            int row = q0 + wave * 32 + mi * 16 + l15;
            const ushort* qp = qkv + (size_t)row * TOTAL + g * GROUP + qh * DHEAD + quad * 8;
#pragma unroll
            for (int ks = 0; ks < 4; ks++)
                qf[mi][ks] = *(const short8*)(qp + ks * 32);
        }

        f32x4 o[2][8];
#pragma unroll
        for (int mi = 0; mi < 2; mi++)
#pragma unroll
            for (int df = 0; df < 8; df++) o[mi][df] = (f32x4)0.0f;
        float l_vec[2][4];
#pragma unroll
        for (int mi = 0; mi < 2; mi++)
#pragma unroll
            for (int r = 0; r < 4; r++) l_vec[mi][r] = 0.0f;

        // per-thread staging slots (32-row tile: 512 f4 K + 512 f4 V, 512 thr)
        const int kr = tid >> 4, kc = tid & 15;       // K rows 0..31
        const int vd = tid >> 2, vc = tid & 3;        // V rows 0..127

        float4 kpre, vpre;
        // prologue: load tile t0, write buf 0, prefetch t0+1
        kpre = *(const float4*)(qkv + (size_t)(t0 * 32 + kr) * TOTAL + koff + kc * 8);
        vpre = *(const float4*)(VT + (size_t)(g * 128 + vd) * S_LEN + t0 * 32 + vc * 8);
        // previous segment's last-iteration barrier guarantees buf0 is free
        *(float4*)(&Kl[0][kr][kc * 8]) = kpre;
        *(float4*)(&Vt[0][vd][vc * 8]) = vpre;
        if (t0 + 1 < t1) {
            const int j1 = (t0 + 1) * 32;
            kpre = *(const float4*)(qkv + (size_t)(j1 + kr) * TOTAL + koff + kc * 8);
            vpre = *(const float4*)(VT + (size_t)(g * 128 + vd) * S_LEN + j1 + vc * 8);
        }
        __syncthreads();

        for (int t = t0; t < t1; t++) {
            const int cur = (t - t0) & 1;

            // stage tile t+1 into the other buffer (overlaps this compute)
            if (t + 1 < t1) {
                *(float4*)(&Kl[cur ^ 1][kr][kc * 8]) = kpre;
                *(float4*)(&Vt[cur ^ 1][vd][vc * 8]) = vpre;
                if (t + 2 < t1) {
                    const int j2 = (t + 2) * 32;
                    kpre = *(const float4*)(qkv + (size_t)(j2 + kr) * TOTAL + koff + kc * 8);
                    vpre = *(const float4*)(VT + (size_t)(g * 128 + vd) * S_LEN + j2 + vc * 8);
                }
            }

            const int j0 = t * 32;
            // S = Q K^T
            f32x4 sacc[2][2];
#pragma unroll
            for (int mi = 0; mi < 2; mi++)
#pragma unroll
                for (int ni = 0; ni < 2; ni++) sacc[mi][ni] = (f32x4)0.0f;
            __builtin_amdgcn_s_setprio(1);
#pragma unroll
            for (int ni = 0; ni < 2; ni++)
#pragma unroll
                for (int ks = 0; ks < 4; ks++) {
                    short8 kf = *(const short8*)(&Kl[cur][ni * 16 + l15][ks * 32 + quad * 8]);
#pragma unroll
                    for (int mi = 0; mi < 2; mi++)
                        sacc[mi][ni] = __builtin_amdgcn_mfma_f32_16x16x32_bf16(
                            qf[mi][ks], kf, sacc[mi][ni], 0, 0, 0);
                }
            __builtin_amdgcn_s_setprio(0);

            // exp (no max subtraction) + causal mask + per-lane l accumulation
#pragma unroll
            for (int mi = 0; mi < 2; mi++) {
                const int base = q0 + wave * 32 + mi * 16;   // wave-uniform
                if (j0 + 31 > base) {
#pragma unroll
                    for (int r = 0; r < 4; r++) {
                        int row_g = base + quad * 4 + r;
                        float rs = 0.0f;
#pragma unroll
                        for (int ni = 0; ni < 2; ni++) {
                            float e = __expf(sacc[mi][ni][r]);
                            int col_g = j0 + ni * 16 + l15;
                            e = (col_g > row_g) ? 0.0f : e;
                            sacc[mi][ni][r] = e;
                            rs += e;
                        }
                        l_vec[mi][r] += rs;
                    }
                } else {
#pragma unroll
                    for (int r = 0; r < 4; r++) {
                        float rs = 0.0f;
#pragma unroll
                        for (int ni = 0; ni < 2; ni++) {
                            float e = __expf(sacc[mi][ni][r]);
                            sacc[mi][ni][r] = e;
                            rs += e;
                        }
                        l_vec[mi][r] += rs;
                    }
                }
                // P: C-layout -> per-wave LDS (same-wave reuse, no barrier)
#pragma unroll
                for (int ni = 0; ni < 2; ni++)
#pragma unroll
                    for (int r = 0; r < 4; r++)
                        Pl[wave][mi * 16 + quad * 4 + r][ni * 16 + l15] =
                            f2bf(sacc[mi][ni][r]);
            }

            // O += P V  (single 32-wide k-step)
            short8 pf[2];
#pragma unroll
            for (int mi = 0; mi < 2; mi++)
                pf[mi] = *(const short8*)(&Pl[wave][mi * 16 + l15][quad * 8]);
            __builtin_amdgcn_s_setprio(1);
#pragma unroll
            for (int df = 0; df < 8; df++) {
                short8 vf = *(const short8*)(&Vt[cur][df * 16 + l15][quad * 8]);
#pragma unroll
                for (int mi = 0; mi < 2; mi++)
                    o[mi][df] = __builtin_amdgcn_mfma_f32_16x16x32_bf16(
                        pf[mi], vf, o[mi][df], 0, 0, 0);
            }
            __builtin_amdgcn_s_setprio(0);

            // buf^1 staged for next iter; prefetch stays in flight.
            lds_barrier();
        }

        // epilogue
        if (seg_slot[s] >= 0) {
            const int sslot = seg_slot[s];
            // unnormalized partial -> atomic accumulate into 256-row slot
#pragma unroll
            for (int mi = 0; mi < 2; mi++)
#pragma unroll
                for (int r = 0; r < 4; r++) {
                    int row_l = wave * 32 + mi * 16 + quad * 4 + r;   // 0..255
                    float l = l_vec[mi][r];
                    l += __shfl_xor(l, 1);
                    l += __shfl_xor(l, 2);
                    l += __shfl_xor(l, 4);
                    l += __shfl_xor(l, 8);
                    if (l15 == 0)
                        atomicAdd(&l_slot[sslot * 256 + row_l], l);
#pragma unroll
                    for (int df = 0; df < 8; df++)
                        atomicAdd(&o_slot[((size_t)sslot * 256 + row_l) * 128
                                          + df * 16 + l15], o[mi][df][r]);
                }
        } else {
#pragma unroll
            for (int mi = 0; mi < 2; mi++)
#pragma unroll
                for (int r = 0; r < 4; r++) {
                    float l = l_vec[mi][r];
                    l += __shfl_xor(l, 1);
                    l += __shfl_xor(l, 2);
                    l += __shfl_xor(l, 4);
                    l += __shfl_xor(l, 8);
                    float inv = 1.0f / l;
                    int row = q0 + wave * 32 + mi * 16 + quad * 4 + r;
#pragma unroll
                    for (int df = 0; df < 8; df++) {
                        float v = o[mi][df][r] * inv;
                        out[(size_t)row * (NHEAD * DHEAD) + head * DHEAD
                            + df * 16 + l15] = f2bf(v);
                    }
                }
        }
    }
}

// ---------------------------------------------------------------------------
// Normalize split-strip slots -> attn (bf16). 256-row slots.
// slots 0..127: heavy strip of (head, p) -> q0 = (15-p)*256
// slots 128..191: light strips of p 4..7 -> q0 = p*256
// ---------------------------------------------------------------------------
__global__ __launch_bounds__(256)
void fixup_norm(const float* __restrict__ o_slot, const float* __restrict__ l_slot,
                ushort* __restrict__ attn)
{
    const int slot = blockIdx.x;          // 0..191
    int head, q0;
    if (slot < 128) {
        head = slot >> 3;
        q0   = (15 - (slot & 7)) * 256;
    } else {
        int s = slot - 128;
        head = s >> 2;
        q0   = (4 + (s & 3)) * 256;
    }
    const int t = threadIdx.x;
#pragma unroll 4
    for (int i = 0; i < 128; i++) {
        int idx = i * 256 + t;            // 0..32767
        int row = idx >> 7, d = idx & 127;
        float l = l_slot[slot * 256 + row];
        float v = o_slot[(size_t)slot * 32768 + idx] / l;
        attn[(size_t)(q0 + row) * HID_DIM + head * DHEAD + d] = f2bf(v);
    }
}

// ---------------------------------------------------------------------------
extern "C" void kernel_launch(void* const* d_in, const int* in_sizes, int n_in,
                              void* d_out, int out_size, void* d_ws, size_t ws_size,
                              hipStream_t stream)
{
    const float* x     = (const float*)d_in[0];
    const float* wqkv  = (const float*)d_in[1];
    const float* wproj = (const float*)d_in[2];
    float* outp = (float*)d_out;

    const size_t n_x     = (size_t)S_LEN * HID_DIM;     // 8,388,608
    const size_t n_wqkv  = (size_t)TOTAL * HID_DIM;     // 6,291,456
    const size_t n_wproj = (size_t)HID_DIM * HID_DIM;   // 4,194,304
    const size_t n_qkv   = (size_t)S_LEN * TOTAL;
    const size_t n_attn  = (size_t)S_LEN * HID_DIM;

    ushort* xb     = (ushort*)d_ws;                     // dead after GEMM1
    ushort* wqkvb  = xb + n_x;                          // dead after GEMM1
    ushort* qkv    = wqkvb + n_wqkv;
    ushort* attn   = qkv + n_qkv;
    ushort* vt     = attn + n_attn;                     // [4][128][4096]
    // reuse dead regions during/after flash:
    // o_slot+l_slot = 192*32768*4 + 192*256*4 = 25.36 MB <= xb+wqkvb (29.36 MB)
    float* o_slot  = (float*)d_ws;
    float* l_slot  = o_slot + (size_t)NSLOT * 32768;
    ushort* wprojb = wqkvb;                             // converted after fixup

    cvt_f32_bf16<<<2048, 256, 0, stream>>>(x, xb, (int)(n_x / 4), 0);
    cvt_f32_bf16<<<2048, 256, 0, stream>>>(wqkv, wqkvb, (int)(n_wqkv / 4), 1);

    // 1) qkv = x @ wqkv^T (+ V^T side-write)
    gemm_bt<ushort, true><<<dim3(TOTAL / 128, S_LEN / 128), 256, 0, stream>>>(
        xb, wqkvb, qkv, vt, S_LEN, TOTAL, HID_DIM);

    // zero the partial-accumulation slots (xb/wqkvb now dead); o+l contiguous
    zero_f4<<<2048, 256, 0, stream>>>((float4*)o_slot,
                                      (int)(((size_t)NSLOT * 32768 + NSLOT * 256) / 4));

    // 2) attention (512 blocks x 8 waves, 2/CU = 16 waves/CU, dbuf pipeline)
    flash_attn<<<512, 512, 0, stream>>>(qkv, vt, attn, o_slot, l_slot);
    fixup_norm<<<NSLOT, 256, 0, stream>>>(o_slot, l_slot, attn);

    // 3) convert wproj (into dead wqkvb region), then out = attn @ wproj^T
    cvt_f32_bf16<<<2048, 256, 0, stream>>>(wproj, wprojb, (int)(n_wproj / 4), 0);
    gemm_bt<float, false><<<dim3(HID_DIM / 128, S_LEN / 128), 256, 0, stream>>>(
        attn, wprojb, outp, nullptr, S_LEN, HID_DIM, HID_DIM);
}